// Round 7
// baseline (842.044 us; speedup 1.0000x reference)
//
#include <hip/hip_runtime.h>
#include <math.h>

#define NC 37
#define NW 30

typedef __attribute__((ext_vector_type(8))) unsigned int su8;
typedef __attribute__((ext_vector_type(4))) unsigned int su4;
typedef __attribute__((ext_vector_type(2))) unsigned int su2;

#define uf(x) __uint_as_float(x)

// Forced scalar-memory loads (compiler will NOT form s_load for global
// weight streams on its own: no invariance proof). Weights are read-only
// for the kernel's lifetime -> K$ path is safe. Offsets are baked hex
// literals; row base pointers are computed in C (uniform -> SGPR pair).
#define SLD8_0(d, p)   asm volatile("s_load_dwordx8 %0, %1, 0x0"  : "=s"(d) : "s"(p))
#define SLD8_32(d, p)  asm volatile("s_load_dwordx8 %0, %1, 0x20" : "=s"(d) : "s"(p))
#define SLD8_64(d, p)  asm volatile("s_load_dwordx8 %0, %1, 0x40" : "=s"(d) : "s"(p))
#define SLD4_96(d, p)  asm volatile("s_load_dwordx4 %0, %1, 0x60" : "=s"(d) : "s"(p))
#define SLD2_112(d, p) asm volatile("s_load_dwordx2 %0, %1, 0x70" : "=s"(d) : "s"(p))
#define SLD2_0(d, p)   asm volatile("s_load_dwordx2 %0, %1, 0x0"  : "=s"(d) : "s"(p))
#define SLD1_0(d, p)   asm volatile("s_load_dword %0, %1, 0x0"    : "=s"(d) : "s"(p))

#define REPEAT30(M) M(0) M(1) M(2) M(3) M(4) M(5) M(6) M(7) M(8) M(9) \
                    M(10) M(11) M(12) M(13) M(14) M(15) M(16) M(17) M(18) M(19) \
                    M(20) M(21) M(22) M(23) M(24) M(25) M(26) M(27) M(28) M(29)

#define RELUF(v) fmaxf((v), 0.0f)
#define IDF(v) (v)

// 30 FMAs consuming a row of weights held in SGPR tuples Aq,Bq,Cq,Dq,Eq.
// Dual accumulators halve the dependency chain. v_fma with 1 SGPR operand
// is legal (max-1-SGPR rule respected).
#define ROW30(SRC) \
  acc0 = fmaf(uf(Aq[0]), SRC##0, acc0);  acc1 = fmaf(uf(Aq[1]), SRC##1, acc1); \
  acc0 = fmaf(uf(Aq[2]), SRC##2, acc0);  acc1 = fmaf(uf(Aq[3]), SRC##3, acc1); \
  acc0 = fmaf(uf(Aq[4]), SRC##4, acc0);  acc1 = fmaf(uf(Aq[5]), SRC##5, acc1); \
  acc0 = fmaf(uf(Aq[6]), SRC##6, acc0);  acc1 = fmaf(uf(Aq[7]), SRC##7, acc1); \
  acc0 = fmaf(uf(Bq[0]), SRC##8, acc0);  acc1 = fmaf(uf(Bq[1]), SRC##9, acc1); \
  acc0 = fmaf(uf(Bq[2]), SRC##10, acc0); acc1 = fmaf(uf(Bq[3]), SRC##11, acc1); \
  acc0 = fmaf(uf(Bq[4]), SRC##12, acc0); acc1 = fmaf(uf(Bq[5]), SRC##13, acc1); \
  acc0 = fmaf(uf(Bq[6]), SRC##14, acc0); acc1 = fmaf(uf(Bq[7]), SRC##15, acc1); \
  acc0 = fmaf(uf(Cq[0]), SRC##16, acc0); acc1 = fmaf(uf(Cq[1]), SRC##17, acc1); \
  acc0 = fmaf(uf(Cq[2]), SRC##18, acc0); acc1 = fmaf(uf(Cq[3]), SRC##19, acc1); \
  acc0 = fmaf(uf(Cq[4]), SRC##20, acc0); acc1 = fmaf(uf(Cq[5]), SRC##21, acc1); \
  acc0 = fmaf(uf(Cq[6]), SRC##22, acc0); acc1 = fmaf(uf(Cq[7]), SRC##23, acc1); \
  acc0 = fmaf(uf(Dq[0]), SRC##24, acc0); acc1 = fmaf(uf(Dq[1]), SRC##25, acc1); \
  acc0 = fmaf(uf(Dq[2]), SRC##26, acc0); acc1 = fmaf(uf(Dq[3]), SRC##27, acc1); \
  acc0 = fmaf(uf(Eq[0]), SRC##28, acc0); acc1 = fmaf(uf(Eq[1]), SRC##29, acc1);

// One 30-wide output row: 6 scalar loads (30 weights + bias), one
// lgkmcnt(0) wait whose "+s" passthrough makes the FMAs depend on it
// (so the compiler cannot hoist consumers above the wait).
#define LROW(o, wp, bp, SRC, DST, APPLY) { \
  su8 Aq, Bq, Cq; su4 Dq; su2 Eq; unsigned int bbv; \
  const float* rp_ = (wp) + (o)*NW; const float* bp_ = (bp) + (o); \
  SLD8_0(Aq, rp_); SLD8_32(Bq, rp_); SLD8_64(Cq, rp_); \
  SLD4_96(Dq, rp_); SLD2_112(Eq, rp_); SLD1_0(bbv, bp_); \
  asm volatile("s_waitcnt lgkmcnt(0)" \
    : "+s"(Aq), "+s"(Bq), "+s"(Cq), "+s"(Dq), "+s"(Eq), "+s"(bbv)); \
  float acc0 = uf(bbv), acc1 = 0.0f; \
  ROW30(SRC) \
  DST = APPLY(acc0 + acc1); }

// Layer-1 output: 2 weights + bias, no ReLU (matches reference).
#define L1OUT(o, wp, bp, DST) { \
  su2 Wv; unsigned int bbv; \
  const float* rp_ = (wp) + 2*(o); const float* bp_ = (bp) + (o); \
  SLD2_0(Wv, rp_); SLD1_0(bbv, bp_); \
  asm volatile("s_waitcnt lgkmcnt(0)" : "+s"(Wv), "+s"(bbv)); \
  DST = fmaf(uf(Wv[0]), x0v, fmaf(uf(Wv[1]), x1v, uf(bbv))); }

// 2->30->30(ReLU)->30(ReLU)->1 MLP; activations are named scalar registers,
// weights stream through SGPRs via forced s_loads.
__device__ __forceinline__ float mlp_eval(
    float x0v, float x1v,
    const float* __restrict__ w1, const float* __restrict__ b1,
    const float* __restrict__ w2, const float* __restrict__ b2,
    const float* __restrict__ w3, const float* __restrict__ b3,
    const float* __restrict__ wo, const float* __restrict__ boP)
{
#define DECLH(i) float h##i;
    REPEAT30(DECLH)
#define DECLG(i) float g##i;
    REPEAT30(DECLG)

#define DO_L1(o) L1OUT(o, w1, b1, h##o)
    REPEAT30(DO_L1)
#define DO_L2(o) LROW(o, w2, b2, h, g##o, RELUF)
    REPEAT30(DO_L2)
#define DO_L3(o) LROW(o, w3, b3, g, h##o, RELUF)
    REPEAT30(DO_L3)

    float res;
    LROW(0, wo, boP, h, res, IDF)
    return res;

#undef DECLH
#undef DECLG
#undef DO_L1
#undef DO_L2
#undef DO_L3
}

// Writes bias into every output slot (atomic-fallback mode only).
__global__ __launch_bounds__(256) void tide_init(float* __restrict__ out,
                                                 const float* __restrict__ bias,
                                                 int n) {
    int i = blockIdx.x * 256 + threadIdx.x;
    if (i < n) out[i] = bias[0];
}

// Sums the 37 per-constituent partial rows + bias (ws mode).
__global__ __launch_bounds__(256) void tide_reduce(const float* __restrict__ ws,
                                                   const float* __restrict__ bias,
                                                   float* __restrict__ out, int B) {
    int b = blockIdx.x * 256 + threadIdx.x;
    if (b >= B) return;
    float s = bias[0];
    #pragma unroll
    for (int c = 0; c < NC; ++c) s += ws[(long)c * B + b];
    out[b] = s;
}

// MODE 0: plain store of per-constituent partial into ws (no atomics, no
// cross-XCD RMW traffic). MODE 1: atomicAdd fallback if ws is too small.
template<int MODE>
__global__ __launch_bounds__(256, 3) void tide_main(
    const float* __restrict__ x, const float* __restrict__ a,
    const float* __restrict__ u, const float* __restrict__ f,
    const float* __restrict__ V, const float* __restrict__ t,
    const float* __restrict__ WH1, const float* __restrict__ bH1,
    const float* __restrict__ WH2, const float* __restrict__ bH2,
    const float* __restrict__ WH3, const float* __restrict__ bH3,
    const float* __restrict__ WHo, const float* __restrict__ bHo,
    const float* __restrict__ WP1, const float* __restrict__ bP1,
    const float* __restrict__ WP2, const float* __restrict__ bP2,
    const float* __restrict__ WP3, const float* __restrict__ bP3,
    const float* __restrict__ WPo, const float* __restrict__ bPo,
    float* __restrict__ dst, int B)
{
    const int c = blockIdx.y;
    const int b = blockIdx.x * 256 + threadIdx.x;
    if (b >= B) return;

    const float x0v = x[2*b];
    const float x1v = x[2*b + 1];

    const float Hv = mlp_eval(x0v, x1v,
                              WH1 + c*NW*2, bH1 + c*NW,
                              WH2 + c*NW*NW, bH2 + c*NW,
                              WH3 + c*NW*NW, bH3 + c*NW,
                              WHo + c*NW, bHo + c);
    const float pv = mlp_eval(x0v, x1v,
                              WP1 + c*NW*2, bP1 + c*NW,
                              WP2 + c*NW*NW, bP2 + c*NW,
                              WP3 + c*NW*NW, bP3 + c*NW,
                              WPo + c*NW, bPo + c);

    const long cb = (long)c * B + b;
    const float phase = V[cb] + a[cb] * t[b] + u[cb] - pv;
    const float contrib = Hv * f[cb] * cosf(phase);

    if (MODE == 0) {
        dst[cb] = contrib;          // per-constituent partial, no atomics
    } else {
        atomicAdd(&dst[b], contrib);
    }
}

extern "C" void kernel_launch(void* const* d_in, const int* in_sizes, int n_in,
                              void* d_out, int out_size, void* d_ws, size_t ws_size,
                              hipStream_t stream) {
    const float* x    = (const float*)d_in[0];
    const float* a    = (const float*)d_in[1];
    const float* u    = (const float*)d_in[2];
    const float* f    = (const float*)d_in[3];
    const float* V    = (const float*)d_in[4];
    const float* t    = (const float*)d_in[5];
    const float* bias = (const float*)d_in[6];
    const float* WH1  = (const float*)d_in[7];
    const float* bH1  = (const float*)d_in[8];
    const float* WH2  = (const float*)d_in[9];
    const float* bH2  = (const float*)d_in[10];
    const float* WH3  = (const float*)d_in[11];
    const float* bH3  = (const float*)d_in[12];
    const float* WHo  = (const float*)d_in[13];
    const float* bHo  = (const float*)d_in[14];
    const float* WP1  = (const float*)d_in[15];
    const float* bP1  = (const float*)d_in[16];
    const float* WP2  = (const float*)d_in[17];
    const float* bP2  = (const float*)d_in[18];
    const float* WP3  = (const float*)d_in[19];
    const float* bP3  = (const float*)d_in[20];
    const float* WPo  = (const float*)d_in[21];
    const float* bPo  = (const float*)d_in[22];
    float* out = (float*)d_out;

    const int B = in_sizes[0] / 2;           // x is [B,2]
    const size_t ws_needed = (size_t)NC * (size_t)B * sizeof(float);

    dim3 grid((B + 255) / 256, NC);
    if (ws_size >= ws_needed) {
        float* ws = (float*)d_ws;
        tide_main<0><<<grid, 256, 0, stream>>>(x, a, u, f, V, t,
                                               WH1, bH1, WH2, bH2, WH3, bH3, WHo, bHo,
                                               WP1, bP1, WP2, bP2, WP3, bP3, WPo, bPo,
                                               ws, B);
        tide_reduce<<<(B + 255) / 256, 256, 0, stream>>>(ws, bias, out, B);
    } else {
        tide_init<<<(out_size + 255) / 256, 256, 0, stream>>>(out, bias, out_size);
        tide_main<1><<<grid, 256, 0, stream>>>(x, a, u, f, V, t,
                                               WH1, bH1, WH2, bH2, WH3, bH3, WHo, bHo,
                                               WP1, bP1, WP2, bP2, WP3, bP3, WPo, bPo,
                                               out, B);
    }
}

// Round 9
// 806.847 us; speedup vs baseline: 1.0436x; 1.0436x over previous
//
#include <hip/hip_runtime.h>
#include <math.h>

#define NC 37
#define NW 30

#define REPEAT30(M) M(0) M(1) M(2) M(3) M(4) M(5) M(6) M(7) M(8) M(9) \
                    M(10) M(11) M(12) M(13) M(14) M(15) M(16) M(17) M(18) M(19) \
                    M(20) M(21) M(22) M(23) M(24) M(25) M(26) M(27) M(28) M(29)

#define RELUF(v) fmaxf((v), 0.0f)
#define IDF(v) (v)

// One float2 weight load (8B-aligned: rows stride 120B, base 8B-aligned)
// feeding two FMAs on independent accumulators. Compile-time k -> lowers to
// global_load_dwordx2 base, offset:8k (one address register per row).
#define P2(k, A, Bv) { const float2 w_ = wp2_[k]; \
  acc0 = fmaf(w_.x, (A), acc0); acc1 = fmaf(w_.y, (Bv), acc1); }

#define ROW30F2(SRC) \
  P2(0,SRC##0,SRC##1)   P2(1,SRC##2,SRC##3)   P2(2,SRC##4,SRC##5) \
  P2(3,SRC##6,SRC##7)   P2(4,SRC##8,SRC##9)   P2(5,SRC##10,SRC##11) \
  P2(6,SRC##12,SRC##13) P2(7,SRC##14,SRC##15) P2(8,SRC##16,SRC##17) \
  P2(9,SRC##18,SRC##19) P2(10,SRC##20,SRC##21) P2(11,SRC##22,SRC##23) \
  P2(12,SRC##24,SRC##25) P2(13,SRC##26,SRC##27) P2(14,SRC##28,SRC##29)

// One 30-wide output neuron: 15 float2 weight loads + scalar bias load,
// 30 FMAs on dual accumulators, optional ReLU.
#define LROW(o, wp, bp, SRC, DST, APPLY) { \
  const float2* wp2_ = (const float2*)((wp) + (o)*NW); \
  float acc0 = (bp)[o], acc1 = 0.0f; \
  ROW30F2(SRC) \
  DST = APPLY(acc0 + acc1); }

// Layer-1 neuron: Linear(2,-), NO ReLU (matches reference).
#define L1OUT(o, wp, bp, DST) { \
  const float2 w_ = *(const float2*)((wp) + 2*(o)); \
  DST = fmaf(w_.x, x0v, fmaf(w_.y, x1v, (bp)[o])); }

// 2->30->30(ReLU)->30(ReLU)->1 MLP; activations are named scalar registers
// (h0..h29, g0..g29), weights stream as float2 vector loads (L1-resident,
// wave-uniform addresses -> broadcast hits).
__device__ __forceinline__ float mlp_eval(
    float x0v, float x1v,
    const float* __restrict__ w1, const float* __restrict__ b1,
    const float* __restrict__ w2, const float* __restrict__ b2,
    const float* __restrict__ w3, const float* __restrict__ b3,
    const float* __restrict__ wo, const float* __restrict__ boP)
{
#define DECLH(i) float h##i;
    REPEAT30(DECLH)
#define DECLG(i) float g##i;
    REPEAT30(DECLG)

#define DO_L1(o) L1OUT(o, w1, b1, h##o)
    REPEAT30(DO_L1)
#define DO_L2(o) LROW(o, w2, b2, h, g##o, RELUF)
    REPEAT30(DO_L2)
#define DO_L3(o) LROW(o, w3, b3, g, h##o, RELUF)
    REPEAT30(DO_L3)

    float res;
    LROW(0, wo, boP, h, res, IDF)
    return res;

#undef DECLH
#undef DECLG
#undef DO_L1
#undef DO_L2
#undef DO_L3
}

// Writes bias into every output slot (atomic-fallback mode only).
__global__ __launch_bounds__(256) void tide_init(float* __restrict__ out,
                                                 const float* __restrict__ bias,
                                                 int n) {
    int i = blockIdx.x * 256 + threadIdx.x;
    if (i < n) out[i] = bias[0];
}

// Sums the 37 per-constituent partial rows + bias (ws mode).
__global__ __launch_bounds__(256) void tide_reduce(const float* __restrict__ ws,
                                                   const float* __restrict__ bias,
                                                   float* __restrict__ out, int B) {
    int b = blockIdx.x * 256 + threadIdx.x;
    if (b >= B) return;
    float s = bias[0];
    #pragma unroll
    for (int c = 0; c < NC; ++c) s += ws[(long)c * B + b];
    out[b] = s;
}

// MODE 0: plain store of per-constituent partial into ws (no atomics, no
// cross-XCD RMW traffic). MODE 1: atomicAdd fallback if ws is too small.
template<int MODE>
__global__ __launch_bounds__(256, 3) void tide_main(
    const float* __restrict__ x, const float* __restrict__ a,
    const float* __restrict__ u, const float* __restrict__ f,
    const float* __restrict__ V, const float* __restrict__ t,
    const float* __restrict__ WH1, const float* __restrict__ bH1,
    const float* __restrict__ WH2, const float* __restrict__ bH2,
    const float* __restrict__ WH3, const float* __restrict__ bH3,
    const float* __restrict__ WHo, const float* __restrict__ bHo,
    const float* __restrict__ WP1, const float* __restrict__ bP1,
    const float* __restrict__ WP2, const float* __restrict__ bP2,
    const float* __restrict__ WP3, const float* __restrict__ bP3,
    const float* __restrict__ WPo, const float* __restrict__ bPo,
    float* __restrict__ dst, int B)
{
    const int c = blockIdx.y;
    const int b = blockIdx.x * 256 + threadIdx.x;
    if (b >= B) return;

    const float2 xv = *(const float2*)(x + 2*b);
    const float x0v = xv.x;
    const float x1v = xv.y;

    const float Hv = mlp_eval(x0v, x1v,
                              WH1 + c*NW*2, bH1 + c*NW,
                              WH2 + c*NW*NW, bH2 + c*NW,
                              WH3 + c*NW*NW, bH3 + c*NW,
                              WHo + c*NW, bHo + c);
    const float pv = mlp_eval(x0v, x1v,
                              WP1 + c*NW*2, bP1 + c*NW,
                              WP2 + c*NW*NW, bP2 + c*NW,
                              WP3 + c*NW*NW, bP3 + c*NW,
                              WPo + c*NW, bPo + c);

    const long cb = (long)c * B + b;
    const float phase = V[cb] + a[cb] * t[b] + u[cb] - pv;
    const float contrib = Hv * f[cb] * cosf(phase);

    if (MODE == 0) {
        dst[cb] = contrib;          // per-constituent partial, no atomics
    } else {
        atomicAdd(&dst[b], contrib);
    }
}

extern "C" void kernel_launch(void* const* d_in, const int* in_sizes, int n_in,
                              void* d_out, int out_size, void* d_ws, size_t ws_size,
                              hipStream_t stream) {
    const float* x    = (const float*)d_in[0];
    const float* a    = (const float*)d_in[1];
    const float* u    = (const float*)d_in[2];
    const float* f    = (const float*)d_in[3];
    const float* V    = (const float*)d_in[4];
    const float* t    = (const float*)d_in[5];
    const float* bias = (const float*)d_in[6];
    const float* WH1  = (const float*)d_in[7];
    const float* bH1  = (const float*)d_in[8];
    const float* WH2  = (const float*)d_in[9];
    const float* bH2  = (const float*)d_in[10];
    const float* WH3  = (const float*)d_in[11];
    const float* bH3  = (const float*)d_in[12];
    const float* WHo  = (const float*)d_in[13];
    const float* bHo  = (const float*)d_in[14];
    const float* WP1  = (const float*)d_in[15];
    const float* bP1  = (const float*)d_in[16];
    const float* WP2  = (const float*)d_in[17];
    const float* bP2  = (const float*)d_in[18];
    const float* WP3  = (const float*)d_in[19];
    const float* bP3  = (const float*)d_in[20];
    const float* WPo  = (const float*)d_in[21];
    const float* bPo  = (const float*)d_in[22];
    float* out = (float*)d_out;

    const int B = in_sizes[0] / 2;           // x is [B,2]
    const size_t ws_needed = (size_t)NC * (size_t)B * sizeof(float);

    dim3 grid((B + 255) / 256, NC);
    if (ws_size >= ws_needed) {
        float* ws = (float*)d_ws;
        tide_main<0><<<grid, 256, 0, stream>>>(x, a, u, f, V, t,
                                               WH1, bH1, WH2, bH2, WH3, bH3, WHo, bHo,
                                               WP1, bP1, WP2, bP2, WP3, bP3, WPo, bPo,
                                               ws, B);
        tide_reduce<<<(B + 255) / 256, 256, 0, stream>>>(ws, bias, out, B);
    } else {
        tide_init<<<(out_size + 255) / 256, 256, 0, stream>>>(out, bias, out_size);
        tide_main<1><<<grid, 256, 0, stream>>>(x, a, u, f, V, t,
                                               WH1, bH1, WH2, bH2, WH3, bH3, WHo, bHo,
                                               WP1, bP1, WP2, bP2, WP3, bP3, WPo, bPo,
                                               out, B);
    }
}